// Round 7
// baseline (306.143 us; speedup 1.0000x reference)
//
#include <hip/hip_runtime.h>
#include <math.h>

// Round 7: attn occupancy (V-hi PV, 32KB LDS, 4 blocks/CU) + period-32 bank
// swizzle key + qkv K/V 1-pass GEMM.
// ws layout (MU = 1M ushorts = 2MB):
//  qh:0 ql:4 kh:8(swz,hi) vth:16(swz,hi) O0:24 O1:28 hsh:32 stats:36
//  WqTh:40 WqTl:41 WkTh:42 WkTl:43 WvTh:44 WvTl:45 WoTh:46 WoTl:47 (96MB)

#define SEQ 2048
#define EMB 1024
#define NH 16
#define HD 64
#define LOG2E 1.44269504088896340736f
#define MU (1u << 20)

typedef short v8s __attribute__((ext_vector_type(8)));
typedef float v4f __attribute__((ext_vector_type(4)));
typedef float v16f __attribute__((ext_vector_type(16)));
typedef unsigned int v4u __attribute__((ext_vector_type(4)));

__device__ __forceinline__ v4f mfma16(v8s a, v8s b, v4f c) {
  return __builtin_amdgcn_mfma_f32_16x16x32_bf16(a, b, c, 0, 0, 0);
}
__device__ __forceinline__ v16f mfma32(v8s a, v8s b, v16f c) {
  return __builtin_amdgcn_mfma_f32_32x32x16_bf16(a, b, c, 0, 0, 0);
}
__device__ __forceinline__ unsigned short bfh(float x) {
  unsigned u = __builtin_bit_cast(unsigned, x);
  return (unsigned short)((u + 0x7FFFu + ((u >> 16) & 1u)) >> 16);
}
__device__ __forceinline__ float bff(unsigned short h) {
  unsigned u = (unsigned)h << 16;
  return __builtin_bit_cast(float, u);
}
__device__ __forceinline__ int imin(int a, int b) { return a < b ? a : b; }
__device__ __forceinline__ unsigned pk2(float a, float b) {
  unsigned h;
  asm("v_cvt_pk_bf16_f32 %0, %1, %2" : "=v"(h) : "v"(a), "v"(b));
  return h;
}
__device__ __forceinline__ void split2(float a, float b, unsigned& uh, unsigned& ul) {
  const unsigned h = pk2(a, b);
  const float ra = __builtin_bit_cast(float, h << 16);
  const float rb = __builtin_bit_cast(float, h & 0xFFFF0000u);
  uh = h;
  ul = pk2(a - ra, b - rb);
}
typedef const __attribute__((address_space(1))) unsigned char* gp_t;
typedef __attribute__((address_space(3))) unsigned char* lp_t;
__device__ __forceinline__ void gload16(const void* g, void* l) {
  __builtin_amdgcn_global_load_lds((gp_t)g, (lp_t)l, 16, 0, 0);
}
// period-32 LDS/granule swizzle key (breaks stride-8 lane aliasing)
__device__ __forceinline__ int skey(int x) {
  return ((x & 7) + ((x >> 3) & 3)) & 7;
}

// ---------------- prepass: hs hi-split + W transpose/split -------------------
__global__ __launch_bounds__(256) void prep_kernel(
    const float* __restrict__ hs, const float* __restrict__ Wq,
    const float* __restrict__ Wk, const float* __restrict__ Wv,
    const float* __restrict__ Wo, unsigned short* __restrict__ wsu) {
  __shared__ float T[64][68];
  const int t = threadIdx.x;
  const int z = blockIdx.z;
  if (z == 4) {  // hs -> bf16 hi only
    unsigned short* ah = wsu + 32u * MU;
    const int base = (blockIdx.y * 16 + blockIdx.x) * 16384 + t * 4;
#pragma unroll
    for (int i = 0; i < 16; ++i) {
      const int idx = base + i * 1024;
      const float4 v = *(const float4*)(hs + idx);
      *(uint2*)&ah[idx] = make_uint2(pk2(v.x, v.y), pk2(v.z, v.w));
    }
    return;
  }
  const float* W = (z == 0) ? Wq : (z == 1) ? Wk : (z == 2) ? Wv : Wo;
  const float s = (z == 0) ? 0.125f * LOG2E : 1.0f;
  const bool wlo = (z == 0 || z == 3);  // K/V mats are 1-pass now
  unsigned short* WTh = wsu + (size_t)(40u + 2u * z) * MU;
  unsigned short* WTl = WTh + MU;
  const int n0 = blockIdx.x * 64, k0 = blockIdx.y * 64;
  const int r = t >> 2, cs = (t & 3) * 16;
#pragma unroll
  for (int i = 0; i < 4; ++i)
    *(float4*)&T[r][cs + i * 4] =
        *(const float4*)(W + (size_t)(k0 + r) * EMB + n0 + cs + i * 4);
  __syncthreads();
  unsigned short hb[16], lb[16];
#pragma unroll
  for (int i = 0; i < 16; i += 2) {
    const float a = T[cs + i][r] * s, b2 = T[cs + i + 1][r] * s;
    unsigned uh, ul = 0;
    if (wlo) split2(a, b2, uh, ul);
    else uh = pk2(a, b2);
    hb[i] = (unsigned short)(uh & 0xFFFFu);
    hb[i + 1] = (unsigned short)(uh >> 16);
    lb[i] = (unsigned short)(ul & 0xFFFFu);
    lb[i + 1] = (unsigned short)(ul >> 16);
  }
  const size_t go = (size_t)(n0 + r) * EMB + k0 + cs;
  *(v8s*)&WTh[go] = *(v8s*)&hb[0];
  *(v8s*)&WTh[go + 8] = *(v8s*)&hb[8];
  if (wlo) {
    *(v8s*)&WTl[go] = *(v8s*)&lb[0];
    *(v8s*)&WTl[go + 8] = *(v8s*)&lb[8];
  }
}

// ------------- 128x128 GEMM (Ah*Bh [+ Ah*Bl]), gload_lds staging -------------
struct alignas(16) G2Smem {
  unsigned short Ah[128][32], Bh[128][32], Bl[128][32];  // 24KB
};

__device__ __forceinline__ void gemm128_bf(
    const unsigned short* __restrict__ Ah_g,
    const unsigned short* __restrict__ Bh_g,
    const unsigned short* __restrict__ Bl_g,
    int m0, int n0, G2Smem& S, v4f acc[4][4], const bool useBl) {
  const int t = threadIdx.x;
  const int l = t & 63, w = t >> 6;
  const int wm = (w >> 1) << 6, wn = (w & 1) << 6;
  const int lg = l >> 4, lc = l & 15;
  const int r0 = t >> 2;
  const int gl = (t & 3) ^ ((r0 >> 1) & 3);
  unsigned short* lba = &S.Ah[0][0] + w * 512;
  unsigned short* lbb = &S.Bh[0][0] + w * 512;
  unsigned short* lbl = &S.Bl[0][0] + w * 512;
  for (int k0 = 0; k0 < EMB; k0 += 32) {
    __syncthreads();
    {
      const size_t sa0 = (size_t)(m0 + r0) * EMB + k0 + gl * 8;
      const size_t sb0 = (size_t)(n0 + r0) * EMB + k0 + gl * 8;
      gload16(Ah_g + sa0, lba);
      gload16(Ah_g + sa0 + (size_t)64 * EMB, lba + 2048);
      gload16(Bh_g + sb0, lbb);
      gload16(Bh_g + sb0 + (size_t)64 * EMB, lbb + 2048);
      if (useBl) {
        gload16(Bl_g + sb0, lbl);
        gload16(Bl_g + sb0 + (size_t)64 * EMB, lbl + 2048);
      }
    }
    asm volatile("s_waitcnt vmcnt(0)" ::: "memory");
    __syncthreads();
    v8s ah[4], bh[4], bl[4];
#pragma unroll
    for (int r = 0; r < 4; ++r) {
      const int ra = wm + r * 16 + lc;
      ah[r] = *(const v8s*)&S.Ah[ra][(lg ^ ((ra >> 1) & 3)) * 8];
      const int rb = wn + r * 16 + lc;
      bh[r] = *(const v8s*)&S.Bh[rb][(lg ^ ((rb >> 1) & 3)) * 8];
      if (useBl) bl[r] = *(const v8s*)&S.Bl[rb][(lg ^ ((rb >> 1) & 3)) * 8];
    }
#pragma unroll
    for (int i = 0; i < 4; ++i)
#pragma unroll
      for (int j = 0; j < 4; ++j) {
        acc[i][j] = mfma16(ah[i], bh[j], acc[i][j]);
        if (useBl) acc[i][j] = mfma16(ah[i], bl[j], acc[i][j]);
      }
  }
  __syncthreads();  // LDS safe to reuse
}

// ---------------- kernel: QKV projection -------------------------------------
__global__ __launch_bounds__(256) void qkv_mfma(
    const float* __restrict__ bq, const float* __restrict__ bk,
    const float* __restrict__ bv, unsigned short* __restrict__ wsu) {
  __shared__ G2Smem S;
  const int mat = blockIdx.y >> 3;
  const int m0 = blockIdx.x << 7, n0 = (blockIdx.y & 7) << 7;
  const unsigned short* Ah_g = wsu + 32u * MU;
  const unsigned short* Bh_g = wsu + (size_t)(40u + 2u * mat) * MU;
  const unsigned short* Bl_g = Bh_g + MU;
  const float* bias = (mat == 0) ? bq : (mat == 1) ? bk : bv;
  unsigned short* oh = wsu + (size_t)mat * 8u * MU;  // q:0 k:8 v(t):16
  unsigned short* ol = oh + 4u * MU;

  v4f acc[4][4] = {};
  gemm128_bf(Ah_g, Bh_g, Bl_g, m0, n0, S, acc, mat == 0);

  const int t = threadIdx.x, l = t & 63, w = t >> 6;
  const int wm = (w >> 1) << 6, wn = (w & 1) << 6, lg = l >> 4, lc = l & 15;
  if (mat == 0) {  // Q: plain [bh][s][d], hi+lo
#pragma unroll
    for (int i = 0; i < 4; ++i)
#pragma unroll
      for (int j = 0; j < 4; ++j)
#pragma unroll
        for (int jr = 0; jr < 4; ++jr) {
          const int r = m0 + wm + i * 16 + lg * 4 + jr;
          const int cm = n0 + wn + j * 16 + lc;
          const float val = acc[i][j][jr] + bias[cm] * (0.125f * LOG2E);
          const unsigned short h = bfh(val);
          const size_t idx = (((size_t)((r >> 11) * NH + (cm >> 6)) * SEQ) +
                              (r & 2047)) * HD + (cm & 63);
          oh[idx] = h;
          ol[idx] = bfh(val - bff(h));
        }
  } else if (mat == 1) {  // K: swizzled granules (period-32 key), hi only
#pragma unroll
    for (int i = 0; i < 4; ++i)
#pragma unroll
      for (int j = 0; j < 4; ++j)
#pragma unroll
        for (int jr = 0; jr < 4; ++jr) {
          const int r = m0 + wm + i * 16 + lg * 4 + jr;
          const int cm = n0 + wn + j * 16 + lc;
          const float val = acc[i][j][jr] + bias[cm];
          const int s = r & 2047, d = cm & 63;
          const size_t idx = (((size_t)((r >> 11) * NH + (cm >> 6)) * SEQ) + s) * HD +
                             ((((d >> 3) ^ skey(s)) << 3) | (d & 7));
          oh[idx] = bfh(val);
        }
  } else {  // V: transpose via LDS -> [bh][d][s] swizzled (period-32 key), hi only
    unsigned short* Traw = &S.Ah[0][0];
    unsigned short (*Th)[136] = (unsigned short(*)[136])Traw;
    const int b = m0 >> 11;
    const int s0base = m0 & 2047;
#pragma unroll
    for (int j = 0; j < 4; ++j) {
      __syncthreads();
#pragma unroll
      for (int i = 0; i < 4; ++i)
#pragma unroll
        for (int jr = 0; jr < 4; ++jr) {
          const int cm = n0 + wn + j * 16 + lc;
          const float val = acc[i][j][jr] + bias[cm];
          const int trow = (wn >> 2) + lc;
          const int tcol = wm + i * 16 + lg * 4 + jr;
          Th[trow][tcol] = bfh(val);
        }
      __syncthreads();
      const int tr = t >> 3, sgc = (t & 7) * 16;
      const int c = n0 + (tr >> 4) * 64 + j * 16 + (tr & 15);
      const int h2 = c >> 6, d = c & 63;
      const int sabs = s0base + sgc;
      const int g0 = (sabs >> 3) & 7;  // even
      const size_t ob = ((size_t)(b * NH + h2) * HD + d) * SEQ + (sabs & ~63);
      const int o0 = (g0 ^ skey(d)) << 3, o1 = ((g0 + 1) ^ skey(d)) << 3;
      *(v8s*)&oh[ob + o0] = *(const v8s*)&Th[tr][sgc];
      *(v8s*)&oh[ob + o1] = *(const v8s*)&Th[tr][sgc + 8];
    }
  }
}

// ---------------- kernel: flash attention (KV-split 2x) ----------------------
__device__ __forceinline__ v8s pfrag(unsigned a0, unsigned a1, unsigned a2,
                                     unsigned a3, int h5) {
  const unsigned sa = (unsigned)__shfl_xor((int)(h5 ? a0 : a2), 32, 64);
  const unsigned sb = (unsigned)__shfl_xor((int)(h5 ? a1 : a3), 32, 64);
  v4u r;
  r[0] = h5 ? sa : a0;
  r[1] = h5 ? sb : a1;
  r[2] = h5 ? a2 : sa;
  r[3] = h5 ? a3 : sb;
  return __builtin_bit_cast(v8s, r);
}

__global__ __launch_bounds__(256, 4) void attn_mfma(
    const float* __restrict__ rel_bias, unsigned short* __restrict__ wsu) {
  __shared__ struct alignas(16) {
    unsigned short Kh[2][64][64];
    unsigned short VTh[2][64][64];
    float bias8[32];
  } S;
  const int t = threadIdx.x;
  const int nid = (blockIdx.x & 7) * 128 + (blockIdx.x >> 3);  // XCD swizzle
  const int half = nid >> 9;
  const int bh = (nid >> 4) & 31;
  const int qt = nid & 15;
  const int hh = bh & 15, b = bh >> 4;
  const int w = t >> 6, l = t & 63;
  const int lq = l & 31, h5 = l >> 5;
  const int qbase = qt * 128 + w * 32;
  const int kvbase = half << 10;
  const int kkey = skey(lq);

  const unsigned short* qh = wsu;
  const unsigned short* ql = wsu + 4u * MU;
  const unsigned short* kh = wsu + 8u * MU;
  const unsigned short* vth = wsu + 16u * MU;
  unsigned short* od = wsu + (half ? 28u : 24u) * MU;
  float2* stats = (float2*)(wsu + 36u * MU);

  if (t < 32) S.bias8[t] = rel_bias[t * NH + hh] * 8.0f * LOG2E;

  v8s qfh[4], qfl[4];
  const size_t qg = ((size_t)bh * SEQ + qbase + lq) * HD;
#pragma unroll
  for (int dc = 0; dc < 4; ++dc) {
    qfh[dc] = *(const v8s*)(qh + qg + dc * 16 + h5 * 8);
    qfl[dc] = *(const v8s*)(ql + qg + dc * 16 + h5 * 8);
  }

  float m_run = -1e30f, l_run = 0.0f;
  v16f acc[2] = {};

  const int srow = t >> 3, sg = t & 7;
  const size_t kbase_g = ((size_t)bh * SEQ + kvbase) * HD;
  const size_t vbase_g = (size_t)bh * HD * SEQ + kvbase;

  auto stage = [&](int kt, int bufsel) {
    const int kv0 = kt * 64;
    unsigned short* lk = &S.Kh[bufsel][0][0] + w * 512;
    unsigned short* lvh = &S.VTh[bufsel][0][0] + w * 512;
    gload16(kh + kbase_g + (size_t)(kv0 + srow) * HD + sg * 8, lk);
    gload16(kh + kbase_g + (size_t)(kv0 + srow + 32) * HD + sg * 8, lk + 2048);
    gload16(vth + vbase_g + (size_t)srow * SEQ + kv0 + sg * 8, lvh);
    gload16(vth + vbase_g + (size_t)(srow + 32) * SEQ + kv0 + sg * 8, lvh + 2048);
  };

  stage(0, 0);
  for (int kt = 0; kt < 16; ++kt) {
    const int buf = kt & 1;
    const int kv0 = kvbase + kt * 64;
    asm volatile("s_waitcnt vmcnt(0)" ::: "memory");
    __syncthreads();
    if (kt < 15) stage(kt + 1, buf ^ 1);

    // ---- QK^T swapped, 2-pass (Kh*Qh + Kh*Ql) ----
    v16f sc[2] = {};
    __builtin_amdgcn_s_setprio(1);
#pragma unroll
    for (int kb = 0; kb < 2; ++kb)
#pragma unroll
      for (int dc = 0; dc < 4; ++dc) {
        const int cswz = (((dc << 1) + h5) ^ kkey) << 3;
        const v8s kfh = *(const v8s*)&S.Kh[buf][kb * 32 + lq][cswz];
        sc[kb] = mfma32(kfh, qfh[dc], sc[kb]);
        sc[kb] = mfma32(kfh, qfl[dc], sc[kb]);
      }
    __builtin_amdgcn_s_setprio(0);

    // ---- rel-pos bias (log2 domain) ----
#pragma unroll
    for (int kb = 0; kb < 2; ++kb) {
      const int dq = qbase - (kv0 + kb * 32);
      if (dq + 31 <= 0) {
        const float bb = S.bias8[0];
#pragma unroll
        for (int r = 0; r < 16; ++r) sc[kb][r] += bb;
      } else if (dq >= 90) {
        const float bb = S.bias8[31];
#pragma unroll
        for (int r = 0; r < 16; ++r) sc[kb][r] += bb;
      } else {
#pragma unroll
        for (int r = 0; r < 16; ++r) {
          const int krow = (r & 3) + 8 * (r >> 2) + 4 * h5;
          int rp = (qbase + lq) - (kv0 + kb * 32 + krow);
          rp = rp > 0 ? rp : 0;
          const int bu =
              rp < 16 ? rp
                      : imin(16 + (int)(8.0f * __log2f((float)rp * 0.0625f)), 31);
          sc[kb][r] += S.bias8[bu];
        }
      }
    }

    // ---- online softmax, defer-max THR=8 ----
    float mt = sc[0][0];
#pragma unroll
    for (int r = 1; r < 16; ++r) mt = fmaxf(mt, sc[0][r]);
#pragma unroll
    for (int r = 0; r < 16; ++r) mt = fmaxf(mt, sc[1][r]);
    mt = fmaxf(mt, __shfl_xor(mt, 32, 64));
    if (__all(mt <= m_run + 8.0f) == 0) {
      const float mn = fmaxf(m_run, mt);
      const float fac = exp2f(m_run - mn);
      l_run *= fac;
#pragma unroll
      for (int r = 0; r < 16; ++r) {
        acc[0][r] *= fac;
        acc[1][r] *= fac;
      }
      m_run = mn;
    }
    unsigned pk[16];
    float rs = 0.0f;
#pragma unroll
    for (int i = 0; i < 16; ++i) {
      const float p0 = exp2f(sc[i >> 3][(2 * i) & 15] - m_run);
      const float p1 = exp2f(sc[i >> 3][(2 * i + 1) & 15] - m_run);
      rs += p0 + p1;
      pk[i] = pk2(p0, p1);
    }
    rs += __shfl_xor(rs, 32, 64);
    l_run += rs;

    // ---- PV 1-pass (Ph*Vh), O^T accumulate ----
    __builtin_amdgcn_s_setprio(1);
#pragma unroll
    for (int ks = 0; ks < 4; ++ks) {
      const v8s pb = pfrag(pk[4 * ks], pk[4 * ks + 1], pk[4 * ks + 2],
                           pk[4 * ks + 3], h5);
      const int vswz = (((ks << 1) + h5) ^ kkey) << 3;
#pragma unroll
      for (int db = 0; db < 2; ++db) {
        const v8s vfh = *(const v8s*)&S.VTh[buf][db * 32 + lq][vswz];
        acc[db] = mfma32(vfh, pb, acc[db]);
      }
    }
    __builtin_amdgcn_s_setprio(0);
  }

  // epilogue: normalized partial O (bf16 hi) + stats
  const float inv = 1.0f / l_run;
  const size_t rowb = ((size_t)b * SEQ + qbase + lq) * EMB + hh * HD;
#pragma unroll
  for (int db = 0; db < 2; ++db)
#pragma unroll
    for (int i = 0; i < 8; ++i) {
      const unsigned u = pk2(acc[db][2 * i] * inv, acc[db][2 * i + 1] * inv);
      const int d0 = db * 32 + 8 * (i >> 1) + 4 * h5 + 2 * (i & 1);
      *(unsigned*)&od[rowb + d0] = u;
    }
  if (h5 == 0)
    stats[(size_t)((half << 5) + bh) * SEQ + qbase + lq] =
        make_float2(m_run, l_run);
}

// ---------------- kernel: merge two KV-halves --------------------------------
__global__ __launch_bounds__(256) void merge_kernel(unsigned short* __restrict__ wsu) {
  const int t = threadIdx.x;
  const size_t idx = ((size_t)blockIdx.x * 256 + t) * 16;
  const int row = (int)(idx >> 10);
  const int col = (int)(idx & 1023);
  const int b = row >> 11, s = row & 2047;
  const int bh = b * NH + (col >> 6);
  const float2* st = (const float2*)(wsu + 36u * MU);
  const float2 s0 = st[(size_t)bh * SEQ + s];
  const float2 s1 = st[(size_t)32 * SEQ + (size_t)bh * SEQ + s];
  const float M = fmaxf(s0.x, s1.x);
  const float w0 = s0.y * exp2f(s0.x - M);
  const float w1 = s1.y * exp2f(s1.x - M);
  const float inv = 1.0f / (w0 + w1);
  const float a0 = w0 * inv, a1 = w1 * inv;
  unsigned short* p0 = wsu + 24u * MU + idx;
  const unsigned short* p1 = wsu + 28u * MU + idx;
  const v8s x0a = *(const v8s*)p0, x0b = *(const v8s*)(p0 + 8);
  const v8s x1a = *(const v8s*)p1, x1b = *(const v8s*)(p1 + 8);
  unsigned short o[16];
#pragma unroll
  for (int e = 0; e < 8; ++e) {
    o[e] = bfh(a0 * bff((unsigned short)x0a[e]) + a1 * bff((unsigned short)x1a[e]));
    o[8 + e] =
        bfh(a0 * bff((unsigned short)x0b[e]) + a1 * bff((unsigned short)x1b[e]));
  }
  *(v8s*)p0 = *(const v8s*)&o[0];
  *(v8s*)(p0 + 8) = *(const v8s*)&o[8];
}

// ---------------- kernel: output projection ----------------------------------
__global__ __launch_bounds__(256) void out_mfma(
    const float* __restrict__ bo, float* __restrict__ out,
    unsigned short* __restrict__ wsu) {
  __shared__ G2Smem S;
  const int m0 = blockIdx.x << 7, n0 = blockIdx.y << 7;
  const unsigned short* Ah_g = wsu + 24u * MU;  // merged ctx (bf16 hi)
  const unsigned short* Bh_g = wsu + 46u * MU;
  const unsigned short* Bl_g = wsu + 47u * MU;
  v4f acc[4][4] = {};
  gemm128_bf(Ah_g, Bh_g, Bl_g, m0, n0, S, acc, true);
  const int t = threadIdx.x, l = t & 63, w = t >> 6;
  const int wm = (w >> 1) << 6, wn = (w & 1) << 6, lg = l >> 4, lc = l & 15;
#pragma unroll
  for (int i = 0; i < 4; ++i)
#pragma unroll
    for (int j = 0; j < 4; ++j)
#pragma unroll
      for (int jr = 0; jr < 4; ++jr) {
        const int r = m0 + wm + i * 16 + lg * 4 + jr;
        const int c = n0 + wn + j * 16 + lc;
        out[(size_t)r * EMB + c] = acc[i][j][jr] + bo[c];
      }
}

extern "C" void kernel_launch(void* const* d_in, const int* in_sizes, int n_in,
                              void* d_out, int out_size, void* d_ws, size_t ws_size,
                              hipStream_t stream) {
  const float* hs = (const float*)d_in[0];
  const float* Wq = (const float*)d_in[1];
  const float* bq = (const float*)d_in[2];
  const float* Wk = (const float*)d_in[3];
  const float* bk = (const float*)d_in[4];
  const float* Wv = (const float*)d_in[5];
  const float* bv = (const float*)d_in[6];
  const float* Wo = (const float*)d_in[7];
  const float* bo = (const float*)d_in[8];
  const float* rb = (const float*)d_in[9];
  unsigned short* wsu = (unsigned short*)d_ws;

  hipLaunchKernelGGL(prep_kernel, dim3(16, 16, 5), dim3(256), 0, stream,
                     hs, Wq, Wk, Wv, Wo, wsu);
  hipLaunchKernelGGL(qkv_mfma, dim3(32, 24), dim3(256), 0, stream, bq, bk, bv, wsu);
  hipLaunchKernelGGL(attn_mfma, dim3(1024), dim3(256), 0, stream, rb, wsu);
  hipLaunchKernelGGL(merge_kernel, dim3(1024), dim3(256), 0, stream, wsu);
  hipLaunchKernelGGL(out_mfma, dim3(32, 8), dim3(256), 0, stream, bo, (float*)d_out, wsu);
}

// Round 8
// 290.830 us; speedup vs baseline: 1.0527x; 1.0527x over previous
//
#include <hip/hip_runtime.h>
#include <math.h>

// Round 8: fix attn write-amplification (coalesced O^T partials + merge/transpose
// kernel), out-proj 1-pass. Attn core unchanged from r7 (KVBLK=64, 32KB LDS,
// 4 blocks/CU, period-32 swizzle key).
// ws layout (MU = 1M ushorts = 2MB):
//  qh:0 ql:4 kh:8(swz,hi) vth:16(swz,hi) OT0:24 OT1:28 hsh->ctx:32 stats:36
//  WqTh:40 WqTl:41 WkTh:42 WkTl:43 WvTh:44 WvTl:45 WoTh:46 WoTl:47 (96MB)

#define SEQ 2048
#define EMB 1024
#define NH 16
#define HD 64
#define LOG2E 1.44269504088896340736f
#define MU (1u << 20)

typedef short v8s __attribute__((ext_vector_type(8)));
typedef float v4f __attribute__((ext_vector_type(4)));
typedef float v16f __attribute__((ext_vector_type(16)));
typedef unsigned int v4u __attribute__((ext_vector_type(4)));

__device__ __forceinline__ v4f mfma16(v8s a, v8s b, v4f c) {
  return __builtin_amdgcn_mfma_f32_16x16x32_bf16(a, b, c, 0, 0, 0);
}
__device__ __forceinline__ v16f mfma32(v8s a, v8s b, v16f c) {
  return __builtin_amdgcn_mfma_f32_32x32x16_bf16(a, b, c, 0, 0, 0);
}
__device__ __forceinline__ unsigned short bfh(float x) {
  unsigned u = __builtin_bit_cast(unsigned, x);
  return (unsigned short)((u + 0x7FFFu + ((u >> 16) & 1u)) >> 16);
}
__device__ __forceinline__ float bff(unsigned short h) {
  unsigned u = (unsigned)h << 16;
  return __builtin_bit_cast(float, u);
}
__device__ __forceinline__ int imin(int a, int b) { return a < b ? a : b; }
__device__ __forceinline__ unsigned pk2(float a, float b) {
  unsigned h;
  asm("v_cvt_pk_bf16_f32 %0, %1, %2" : "=v"(h) : "v"(a), "v"(b));
  return h;
}
__device__ __forceinline__ void split2(float a, float b, unsigned& uh, unsigned& ul) {
  const unsigned h = pk2(a, b);
  const float ra = __builtin_bit_cast(float, h << 16);
  const float rb = __builtin_bit_cast(float, h & 0xFFFF0000u);
  uh = h;
  ul = pk2(a - ra, b - rb);
}
typedef const __attribute__((address_space(1))) unsigned char* gp_t;
typedef __attribute__((address_space(3))) unsigned char* lp_t;
__device__ __forceinline__ void gload16(const void* g, void* l) {
  __builtin_amdgcn_global_load_lds((gp_t)g, (lp_t)l, 16, 0, 0);
}
// period-32 LDS/granule swizzle key (breaks stride-8 lane aliasing)
__device__ __forceinline__ int skey(int x) {
  return ((x & 7) + ((x >> 3) & 3)) & 7;
}

// ---------------- prepass: hs hi-split + W transpose/split -------------------
__global__ __launch_bounds__(256) void prep_kernel(
    const float* __restrict__ hs, const float* __restrict__ Wq,
    const float* __restrict__ Wk, const float* __restrict__ Wv,
    const float* __restrict__ Wo, unsigned short* __restrict__ wsu) {
  __shared__ float T[64][68];
  const int t = threadIdx.x;
  const int z = blockIdx.z;
  if (z == 4) {  // hs -> bf16 hi only
    unsigned short* ah = wsu + 32u * MU;
    const int base = (blockIdx.y * 16 + blockIdx.x) * 16384 + t * 4;
#pragma unroll
    for (int i = 0; i < 16; ++i) {
      const int idx = base + i * 1024;
      const float4 v = *(const float4*)(hs + idx);
      *(uint2*)&ah[idx] = make_uint2(pk2(v.x, v.y), pk2(v.z, v.w));
    }
    return;
  }
  const float* W = (z == 0) ? Wq : (z == 1) ? Wk : (z == 2) ? Wv : Wo;
  const float s = (z == 0) ? 0.125f * LOG2E : 1.0f;
  const bool wlo = (z == 0);  // only Wq needs the lo plane now
  unsigned short* WTh = wsu + (size_t)(40u + 2u * z) * MU;
  unsigned short* WTl = WTh + MU;
  const int n0 = blockIdx.x * 64, k0 = blockIdx.y * 64;
  const int r = t >> 2, cs = (t & 3) * 16;
#pragma unroll
  for (int i = 0; i < 4; ++i)
    *(float4*)&T[r][cs + i * 4] =
        *(const float4*)(W + (size_t)(k0 + r) * EMB + n0 + cs + i * 4);
  __syncthreads();
  unsigned short hb[16], lb[16];
#pragma unroll
  for (int i = 0; i < 16; i += 2) {
    const float a = T[cs + i][r] * s, b2 = T[cs + i + 1][r] * s;
    unsigned uh, ul = 0;
    if (wlo) split2(a, b2, uh, ul);
    else uh = pk2(a, b2);
    hb[i] = (unsigned short)(uh & 0xFFFFu);
    hb[i + 1] = (unsigned short)(uh >> 16);
    lb[i] = (unsigned short)(ul & 0xFFFFu);
    lb[i + 1] = (unsigned short)(ul >> 16);
  }
  const size_t go = (size_t)(n0 + r) * EMB + k0 + cs;
  *(v8s*)&WTh[go] = *(v8s*)&hb[0];
  *(v8s*)&WTh[go + 8] = *(v8s*)&hb[8];
  if (wlo) {
    *(v8s*)&WTl[go] = *(v8s*)&lb[0];
    *(v8s*)&WTl[go + 8] = *(v8s*)&lb[8];
  }
}

// ------------- 128x128 GEMM (Ah*Bh [+ Ah*Bl]), gload_lds staging -------------
struct alignas(16) G2Smem {
  unsigned short Ah[128][32], Bh[128][32], Bl[128][32];  // 24KB
};

__device__ __forceinline__ void gemm128_bf(
    const unsigned short* __restrict__ Ah_g,
    const unsigned short* __restrict__ Bh_g,
    const unsigned short* __restrict__ Bl_g,
    int m0, int n0, G2Smem& S, v4f acc[4][4], const bool useBl) {
  const int t = threadIdx.x;
  const int l = t & 63, w = t >> 6;
  const int wm = (w >> 1) << 6, wn = (w & 1) << 6;
  const int lg = l >> 4, lc = l & 15;
  const int r0 = t >> 2;
  const int gl = (t & 3) ^ ((r0 >> 1) & 3);
  unsigned short* lba = &S.Ah[0][0] + w * 512;
  unsigned short* lbb = &S.Bh[0][0] + w * 512;
  unsigned short* lbl = &S.Bl[0][0] + w * 512;
  for (int k0 = 0; k0 < EMB; k0 += 32) {
    __syncthreads();
    {
      const size_t sa0 = (size_t)(m0 + r0) * EMB + k0 + gl * 8;
      const size_t sb0 = (size_t)(n0 + r0) * EMB + k0 + gl * 8;
      gload16(Ah_g + sa0, lba);
      gload16(Ah_g + sa0 + (size_t)64 * EMB, lba + 2048);
      gload16(Bh_g + sb0, lbb);
      gload16(Bh_g + sb0 + (size_t)64 * EMB, lbb + 2048);
      if (useBl) {
        gload16(Bl_g + sb0, lbl);
        gload16(Bl_g + sb0 + (size_t)64 * EMB, lbl + 2048);
      }
    }
    asm volatile("s_waitcnt vmcnt(0)" ::: "memory");
    __syncthreads();
    v8s ah[4], bh[4], bl[4];
#pragma unroll
    for (int r = 0; r < 4; ++r) {
      const int ra = wm + r * 16 + lc;
      ah[r] = *(const v8s*)&S.Ah[ra][(lg ^ ((ra >> 1) & 3)) * 8];
      const int rb = wn + r * 16 + lc;
      bh[r] = *(const v8s*)&S.Bh[rb][(lg ^ ((rb >> 1) & 3)) * 8];
      if (useBl) bl[r] = *(const v8s*)&S.Bl[rb][(lg ^ ((rb >> 1) & 3)) * 8];
    }
#pragma unroll
    for (int i = 0; i < 4; ++i)
#pragma unroll
      for (int j = 0; j < 4; ++j) {
        acc[i][j] = mfma16(ah[i], bh[j], acc[i][j]);
        if (useBl) acc[i][j] = mfma16(ah[i], bl[j], acc[i][j]);
      }
  }
  __syncthreads();  // LDS safe to reuse
}

// ---------------- kernel: QKV projection -------------------------------------
__global__ __launch_bounds__(256) void qkv_mfma(
    const float* __restrict__ bq, const float* __restrict__ bk,
    const float* __restrict__ bv, unsigned short* __restrict__ wsu) {
  __shared__ G2Smem S;
  const int mat = blockIdx.y >> 3;
  const int m0 = blockIdx.x << 7, n0 = (blockIdx.y & 7) << 7;
  const unsigned short* Ah_g = wsu + 32u * MU;
  const unsigned short* Bh_g = wsu + (size_t)(40u + 2u * mat) * MU;
  const unsigned short* Bl_g = Bh_g + MU;
  const float* bias = (mat == 0) ? bq : (mat == 1) ? bk : bv;
  unsigned short* oh = wsu + (size_t)mat * 8u * MU;  // q:0 k:8 v(t):16
  unsigned short* ol = oh + 4u * MU;

  v4f acc[4][4] = {};
  gemm128_bf(Ah_g, Bh_g, Bl_g, m0, n0, S, acc, mat == 0);

  const int t = threadIdx.x, l = t & 63, w = t >> 6;
  const int wm = (w >> 1) << 6, wn = (w & 1) << 6, lg = l >> 4, lc = l & 15;
  if (mat == 0) {  // Q: plain [bh][s][d], hi+lo
#pragma unroll
    for (int i = 0; i < 4; ++i)
#pragma unroll
      for (int j = 0; j < 4; ++j)
#pragma unroll
        for (int jr = 0; jr < 4; ++jr) {
          const int r = m0 + wm + i * 16 + lg * 4 + jr;
          const int cm = n0 + wn + j * 16 + lc;
          const float val = acc[i][j][jr] + bias[cm] * (0.125f * LOG2E);
          const unsigned short h = bfh(val);
          const size_t idx = (((size_t)((r >> 11) * NH + (cm >> 6)) * SEQ) +
                              (r & 2047)) * HD + (cm & 63);
          oh[idx] = h;
          ol[idx] = bfh(val - bff(h));
        }
  } else if (mat == 1) {  // K: swizzled granules (period-32 key), hi only
#pragma unroll
    for (int i = 0; i < 4; ++i)
#pragma unroll
      for (int j = 0; j < 4; ++j)
#pragma unroll
        for (int jr = 0; jr < 4; ++jr) {
          const int r = m0 + wm + i * 16 + lg * 4 + jr;
          const int cm = n0 + wn + j * 16 + lc;
          const float val = acc[i][j][jr] + bias[cm];
          const int s = r & 2047, d = cm & 63;
          const size_t idx = (((size_t)((r >> 11) * NH + (cm >> 6)) * SEQ) + s) * HD +
                             ((((d >> 3) ^ skey(s)) << 3) | (d & 7));
          oh[idx] = bfh(val);
        }
  } else {  // V: transpose via LDS -> [bh][d][s] swizzled (period-32 key), hi only
    unsigned short* Traw = &S.Ah[0][0];
    unsigned short (*Th)[136] = (unsigned short(*)[136])Traw;
    const int b = m0 >> 11;
    const int s0base = m0 & 2047;
#pragma unroll
    for (int j = 0; j < 4; ++j) {
      __syncthreads();
#pragma unroll
      for (int i = 0; i < 4; ++i)
#pragma unroll
        for (int jr = 0; jr < 4; ++jr) {
          const int cm = n0 + wn + j * 16 + lc;
          const float val = acc[i][j][jr] + bias[cm];
          const int trow = (wn >> 2) + lc;
          const int tcol = wm + i * 16 + lg * 4 + jr;
          Th[trow][tcol] = bfh(val);
        }
      __syncthreads();
      const int tr = t >> 3, sgc = (t & 7) * 16;
      const int c = n0 + (tr >> 4) * 64 + j * 16 + (tr & 15);
      const int h2 = c >> 6, d = c & 63;
      const int sabs = s0base + sgc;
      const int g0 = (sabs >> 3) & 7;  // even
      const size_t ob = ((size_t)(b * NH + h2) * HD + d) * SEQ + (sabs & ~63);
      const int o0 = (g0 ^ skey(d)) << 3, o1 = ((g0 + 1) ^ skey(d)) << 3;
      *(v8s*)&oh[ob + o0] = *(const v8s*)&Th[tr][sgc];
      *(v8s*)&oh[ob + o1] = *(const v8s*)&Th[tr][sgc + 8];
    }
  }
}

// ---------------- kernel: flash attention (KV-split 2x) ----------------------
__device__ __forceinline__ v8s pfrag(unsigned a0, unsigned a1, unsigned a2,
                                     unsigned a3, int h5) {
  const unsigned sa = (unsigned)__shfl_xor((int)(h5 ? a0 : a2), 32, 64);
  const unsigned sb = (unsigned)__shfl_xor((int)(h5 ? a1 : a3), 32, 64);
  v4u r;
  r[0] = h5 ? sa : a0;
  r[1] = h5 ? sb : a1;
  r[2] = h5 ? a2 : sa;
  r[3] = h5 ? a3 : sb;
  return __builtin_bit_cast(v8s, r);
}

__global__ __launch_bounds__(256, 4) void attn_mfma(
    const float* __restrict__ rel_bias, unsigned short* __restrict__ wsu) {
  __shared__ struct alignas(16) {
    unsigned short Kh[2][64][64];
    unsigned short VTh[2][64][64];
    float bias8[32];
  } S;
  const int t = threadIdx.x;
  const int nid = (blockIdx.x & 7) * 128 + (blockIdx.x >> 3);  // XCD swizzle
  const int half = nid >> 9;
  const int bh = (nid >> 4) & 31;
  const int qt = nid & 15;
  const int hh = bh & 15;
  const int w = t >> 6, l = t & 63;
  const int lq = l & 31, h5 = l >> 5;
  const int qbase = qt * 128 + w * 32;
  const int kvbase = half << 10;
  const int kkey = skey(lq);

  const unsigned short* qh = wsu;
  const unsigned short* ql = wsu + 4u * MU;
  const unsigned short* kh = wsu + 8u * MU;
  const unsigned short* vth = wsu + 16u * MU;
  unsigned short* odT = wsu + (half ? 28u : 24u) * MU;  // [bh][d][s]
  float2* stats = (float2*)(wsu + 36u * MU);

  if (t < 32) S.bias8[t] = rel_bias[t * NH + hh] * 8.0f * LOG2E;

  v8s qfh[4], qfl[4];
  const size_t qg = ((size_t)bh * SEQ + qbase + lq) * HD;
#pragma unroll
  for (int dc = 0; dc < 4; ++dc) {
    qfh[dc] = *(const v8s*)(qh + qg + dc * 16 + h5 * 8);
    qfl[dc] = *(const v8s*)(ql + qg + dc * 16 + h5 * 8);
  }

  float m_run = -1e30f, l_run = 0.0f;
  v16f acc[2] = {};

  const int srow = t >> 3, sg = t & 7;
  const size_t kbase_g = ((size_t)bh * SEQ + kvbase) * HD;
  const size_t vbase_g = (size_t)bh * HD * SEQ + kvbase;

  auto stage = [&](int kt, int bufsel) {
    const int kv0 = kt * 64;
    unsigned short* lk = &S.Kh[bufsel][0][0] + w * 512;
    unsigned short* lvh = &S.VTh[bufsel][0][0] + w * 512;
    gload16(kh + kbase_g + (size_t)(kv0 + srow) * HD + sg * 8, lk);
    gload16(kh + kbase_g + (size_t)(kv0 + srow + 32) * HD + sg * 8, lk + 2048);
    gload16(vth + vbase_g + (size_t)srow * SEQ + kv0 + sg * 8, lvh);
    gload16(vth + vbase_g + (size_t)(srow + 32) * SEQ + kv0 + sg * 8, lvh + 2048);
  };

  stage(0, 0);
  for (int kt = 0; kt < 16; ++kt) {
    const int buf = kt & 1;
    const int kv0 = kvbase + kt * 64;
    asm volatile("s_waitcnt vmcnt(0)" ::: "memory");
    __syncthreads();
    if (kt < 15) stage(kt + 1, buf ^ 1);

    // ---- QK^T swapped, 2-pass (Kh*Qh + Kh*Ql) ----
    v16f sc[2] = {};
    __builtin_amdgcn_s_setprio(1);
#pragma unroll
    for (int kb = 0; kb < 2; ++kb)
#pragma unroll
      for (int dc = 0; dc < 4; ++dc) {
        const int cswz = (((dc << 1) + h5) ^ kkey) << 3;
        const v8s kfh = *(const v8s*)&S.Kh[buf][kb * 32 + lq][cswz];
        sc[kb] = mfma32(kfh, qfh[dc], sc[kb]);
        sc[kb] = mfma32(kfh, qfl[dc], sc[kb]);
      }
    __builtin_amdgcn_s_setprio(0);

    // ---- rel-pos bias (log2 domain) ----
#pragma unroll
    for (int kb = 0; kb < 2; ++kb) {
      const int dq = qbase - (kv0 + kb * 32);
      if (dq + 31 <= 0) {
        const float bb = S.bias8[0];
#pragma unroll
        for (int r = 0; r < 16; ++r) sc[kb][r] += bb;
      } else if (dq >= 90) {
        const float bb = S.bias8[31];
#pragma unroll
        for (int r = 0; r < 16; ++r) sc[kb][r] += bb;
      } else {
#pragma unroll
        for (int r = 0; r < 16; ++r) {
          const int krow = (r & 3) + 8 * (r >> 2) + 4 * h5;
          int rp = (qbase + lq) - (kv0 + kb * 32 + krow);
          rp = rp > 0 ? rp : 0;
          const int bu =
              rp < 16 ? rp
                      : imin(16 + (int)(8.0f * __log2f((float)rp * 0.0625f)), 31);
          sc[kb][r] += S.bias8[bu];
        }
      }
    }

    // ---- online softmax, defer-max THR=8 ----
    float mt = sc[0][0];
#pragma unroll
    for (int r = 1; r < 16; ++r) mt = fmaxf(mt, sc[0][r]);
#pragma unroll
    for (int r = 0; r < 16; ++r) mt = fmaxf(mt, sc[1][r]);
    mt = fmaxf(mt, __shfl_xor(mt, 32, 64));
    if (__all(mt <= m_run + 8.0f) == 0) {
      const float mn = fmaxf(m_run, mt);
      const float fac = exp2f(m_run - mn);
      l_run *= fac;
#pragma unroll
      for (int r = 0; r < 16; ++r) {
        acc[0][r] *= fac;
        acc[1][r] *= fac;
      }
      m_run = mn;
    }
    unsigned pk[16];
    float rs = 0.0f;
#pragma unroll
    for (int i = 0; i < 16; ++i) {
      const float p0 = exp2f(sc[i >> 3][(2 * i) & 15] - m_run);
      const float p1 = exp2f(sc[i >> 3][(2 * i + 1) & 15] - m_run);
      rs += p0 + p1;
      pk[i] = pk2(p0, p1);
    }
    rs += __shfl_xor(rs, 32, 64);
    l_run += rs;

    // ---- PV 1-pass (Ph*Vh), O^T accumulate ----
    __builtin_amdgcn_s_setprio(1);
#pragma unroll
    for (int ks = 0; ks < 4; ++ks) {
      const v8s pb = pfrag(pk[4 * ks], pk[4 * ks + 1], pk[4 * ks + 2],
                           pk[4 * ks + 3], h5);
      const int vswz = (((ks << 1) + h5) ^ kkey) << 3;
#pragma unroll
      for (int db = 0; db < 2; ++db) {
        const v8s vfh = *(const v8s*)&S.VTh[buf][db * 32 + lq][vswz];
        acc[db] = mfma32(vfh, pb, acc[db]);
      }
    }
    __builtin_amdgcn_s_setprio(0);
  }

  // epilogue: COALESCED O^T partial write — [bh][d][s], 64B line per half-wave
  const float inv = 1.0f / l_run;
  const size_t ob = (size_t)bh * HD * SEQ;
#pragma unroll
  for (int db = 0; db < 2; ++db)
#pragma unroll
    for (int r = 0; r < 16; ++r) {
      const int d = db * 32 + (r & 3) + 8 * (r >> 2) + 4 * h5;
      odT[ob + (size_t)d * SEQ + qbase + lq] = bfh(acc[db][r] * inv);
    }
  if (h5 == 0)
    stats[(size_t)((half << 5) + bh) * SEQ + qbase + lq] =
        make_float2(m_run, l_run);
}

// ---------------- kernel: merge halves + transpose O^T -> ctx ----------------
__global__ __launch_bounds__(256) void merge_kernel(unsigned short* __restrict__ wsu) {
  __shared__ unsigned short T[64][72];  // [s-local][d]
  __shared__ float2 AB[64];             // per-s blend factors (a0, a1)
  const int t = threadIdx.x;
  const int s0 = blockIdx.x * 64;  // 32
  const int bh = blockIdx.y;       // 32
  const int b = bh >> 4, hh = bh & 15;
  const unsigned short* o0 = wsu + 24u * MU;
  const unsigned short* o1 = wsu + 28u * MU;
  unsigned short* ctx = wsu + 32u * MU;
  const float2* st = (const float2*)(wsu + 36u * MU);
  if (t < 64) {
    const float2 a = st[(size_t)bh * SEQ + s0 + t];
    const float2 c = st[(size_t)(32 + bh) * SEQ + s0 + t];
    const float M = fmaxf(a.x, c.x);
    const float w0 = a.y * exp2f(a.x - M);
    const float w1 = c.y * exp2f(c.x - M);
    const float inv = 1.0f / (w0 + w1);
    AB[t] = make_float2(w0 * inv, w1 * inv);
  }
  __syncthreads();
  const int r = t >> 2, cs = (t & 3) * 16;  // r = d row, cs = s offset
  const size_t g = ((size_t)bh * HD + r) * SEQ + s0 + cs;
  const v8s x0a = *(const v8s*)(o0 + g), x0b = *(const v8s*)(o0 + g + 8);
  const v8s x1a = *(const v8s*)(o1 + g), x1b = *(const v8s*)(o1 + g + 8);
#pragma unroll
  for (int i = 0; i < 8; ++i) {
    const float2 ab0 = AB[cs + i];
    T[cs + i][r] = bfh(ab0.x * bff((unsigned short)x0a[i]) +
                       ab0.y * bff((unsigned short)x1a[i]));
    const float2 ab1 = AB[cs + 8 + i];
    T[cs + 8 + i][r] = bfh(ab1.x * bff((unsigned short)x0b[i]) +
                           ab1.y * bff((unsigned short)x1b[i]));
  }
  __syncthreads();
  // write ctx [b][s][E]: row = s0 + r, cols hh*64 + cs..cs+16
  const size_t co = ((size_t)b * SEQ + s0 + r) * EMB + hh * HD + cs;
  *(v8s*)&ctx[co] = *(const v8s*)&T[r][cs];
  *(v8s*)&ctx[co + 8] = *(const v8s*)&T[r][cs + 8];
}

// ---------------- kernel: output projection (1-pass) -------------------------
__global__ __launch_bounds__(256) void out_mfma(
    const float* __restrict__ bo, float* __restrict__ out,
    unsigned short* __restrict__ wsu) {
  __shared__ G2Smem S;
  const int m0 = blockIdx.x << 7, n0 = blockIdx.y << 7;
  const unsigned short* Ah_g = wsu + 32u * MU;  // merged ctx (bf16 hi)
  const unsigned short* Bh_g = wsu + 46u * MU;
  const unsigned short* Bl_g = wsu + 47u * MU;
  v4f acc[4][4] = {};
  gemm128_bf(Ah_g, Bh_g, Bl_g, m0, n0, S, acc, false);
  const int t = threadIdx.x, l = t & 63, w = t >> 6;
  const int wm = (w >> 1) << 6, wn = (w & 1) << 6, lg = l >> 4, lc = l & 15;
#pragma unroll
  for (int i = 0; i < 4; ++i)
#pragma unroll
    for (int j = 0; j < 4; ++j)
#pragma unroll
      for (int jr = 0; jr < 4; ++jr) {
        const int r = m0 + wm + i * 16 + lg * 4 + jr;
        const int c = n0 + wn + j * 16 + lc;
        out[(size_t)r * EMB + c] = acc[i][j][jr] + bo[c];
      }
}

extern "C" void kernel_launch(void* const* d_in, const int* in_sizes, int n_in,
                              void* d_out, int out_size, void* d_ws, size_t ws_size,
                              hipStream_t stream) {
  const float* hs = (const float*)d_in[0];
  const float* Wq = (const float*)d_in[1];
  const float* bq = (const float*)d_in[2];
  const float* Wk = (const float*)d_in[3];
  const float* bk = (const float*)d_in[4];
  const float* Wv = (const float*)d_in[5];
  const float* bv = (const float*)d_in[6];
  const float* Wo = (const float*)d_in[7];
  const float* bo = (const float*)d_in[8];
  const float* rb = (const float*)d_in[9];
  unsigned short* wsu = (unsigned short*)d_ws;

  hipLaunchKernelGGL(prep_kernel, dim3(16, 16, 5), dim3(256), 0, stream,
                     hs, Wq, Wk, Wv, Wo, wsu);
  hipLaunchKernelGGL(qkv_mfma, dim3(32, 24), dim3(256), 0, stream, bq, bk, bv, wsu);
  hipLaunchKernelGGL(attn_mfma, dim3(1024), dim3(256), 0, stream, rb, wsu);
  hipLaunchKernelGGL(merge_kernel, dim3(32, 32), dim3(256), 0, stream, wsu);
  hipLaunchKernelGGL(out_mfma, dim3(32, 8), dim3(256), 0, stream, bo, (float*)d_out, wsu);
}

// Round 9
// 258.415 us; speedup vs baseline: 1.1847x; 1.1254x over previous
//
#include <hip/hip_runtime.h>
#include <math.h>

// Round 9: fixed-base softmax (C=12, no max tracking), uniform-bias folded into
// exp base, inline v_exp_f32, tree row-sum. Merge = l-weighted blend (no exp).
// Everything outside attn/merge identical to round 8.
// ws layout (MU = 1M ushorts = 2MB):
//  qh:0 ql:4 kh:8(swz,hi) vth:16(swz,hi) OT0:24 OT1:28 hsh->ctx:32 stats:36(f32 l)
//  WqTh:40 WqTl:41 WkTh:42 WkTl:43 WvTh:44 WvTl:45 WoTh:46 WoTl:47 (96MB)

#define SEQ 2048
#define EMB 1024
#define NH 16
#define HD 64
#define LOG2E 1.44269504088896340736f
#define CBASE 12.0f
#define MU (1u << 20)

typedef short v8s __attribute__((ext_vector_type(8)));
typedef float v4f __attribute__((ext_vector_type(4)));
typedef float v16f __attribute__((ext_vector_type(16)));
typedef unsigned int v4u __attribute__((ext_vector_type(4)));

__device__ __forceinline__ v4f mfma16(v8s a, v8s b, v4f c) {
  return __builtin_amdgcn_mfma_f32_16x16x32_bf16(a, b, c, 0, 0, 0);
}
__device__ __forceinline__ v16f mfma32(v8s a, v8s b, v16f c) {
  return __builtin_amdgcn_mfma_f32_32x32x16_bf16(a, b, c, 0, 0, 0);
}
__device__ __forceinline__ unsigned short bfh(float x) {
  unsigned u = __builtin_bit_cast(unsigned, x);
  return (unsigned short)((u + 0x7FFFu + ((u >> 16) & 1u)) >> 16);
}
__device__ __forceinline__ float bff(unsigned short h) {
  unsigned u = (unsigned)h << 16;
  return __builtin_bit_cast(float, u);
}
__device__ __forceinline__ int imin(int a, int b) { return a < b ? a : b; }
__device__ __forceinline__ unsigned pk2(float a, float b) {
  unsigned h;
  asm("v_cvt_pk_bf16_f32 %0, %1, %2" : "=v"(h) : "v"(a), "v"(b));
  return h;
}
__device__ __forceinline__ float exp2a(float x) {  // raw v_exp_f32 (D = 2^S0)
  float r;
  asm("v_exp_f32 %0, %1" : "=v"(r) : "v"(x));
  return r;
}
__device__ __forceinline__ void split2(float a, float b, unsigned& uh, unsigned& ul) {
  const unsigned h = pk2(a, b);
  const float ra = __builtin_bit_cast(float, h << 16);
  const float rb = __builtin_bit_cast(float, h & 0xFFFF0000u);
  uh = h;
  ul = pk2(a - ra, b - rb);
}
typedef const __attribute__((address_space(1))) unsigned char* gp_t;
typedef __attribute__((address_space(3))) unsigned char* lp_t;
__device__ __forceinline__ void gload16(const void* g, void* l) {
  __builtin_amdgcn_global_load_lds((gp_t)g, (lp_t)l, 16, 0, 0);
}
// period-32 LDS/granule swizzle key (breaks stride-8 lane aliasing)
__device__ __forceinline__ int skey(int x) {
  return ((x & 7) + ((x >> 3) & 3)) & 7;
}

// ---------------- prepass: hs hi-split + W transpose/split -------------------
__global__ __launch_bounds__(256) void prep_kernel(
    const float* __restrict__ hs, const float* __restrict__ Wq,
    const float* __restrict__ Wk, const float* __restrict__ Wv,
    const float* __restrict__ Wo, unsigned short* __restrict__ wsu) {
  __shared__ float T[64][68];
  const int t = threadIdx.x;
  const int z = blockIdx.z;
  if (z == 4) {  // hs -> bf16 hi only
    unsigned short* ah = wsu + 32u * MU;
    const int base = (blockIdx.y * 16 + blockIdx.x) * 16384 + t * 4;
#pragma unroll
    for (int i = 0; i < 16; ++i) {
      const int idx = base + i * 1024;
      const float4 v = *(const float4*)(hs + idx);
      *(uint2*)&ah[idx] = make_uint2(pk2(v.x, v.y), pk2(v.z, v.w));
    }
    return;
  }
  const float* W = (z == 0) ? Wq : (z == 1) ? Wk : (z == 2) ? Wv : Wo;
  const float s = (z == 0) ? 0.125f * LOG2E : 1.0f;
  const bool wlo = (z == 0);  // only Wq needs the lo plane
  unsigned short* WTh = wsu + (size_t)(40u + 2u * z) * MU;
  unsigned short* WTl = WTh + MU;
  const int n0 = blockIdx.x * 64, k0 = blockIdx.y * 64;
  const int r = t >> 2, cs = (t & 3) * 16;
#pragma unroll
  for (int i = 0; i < 4; ++i)
    *(float4*)&T[r][cs + i * 4] =
        *(const float4*)(W + (size_t)(k0 + r) * EMB + n0 + cs + i * 4);
  __syncthreads();
  unsigned short hb[16], lb[16];
#pragma unroll
  for (int i = 0; i < 16; i += 2) {
    const float a = T[cs + i][r] * s, b2 = T[cs + i + 1][r] * s;
    unsigned uh, ul = 0;
    if (wlo) split2(a, b2, uh, ul);
    else uh = pk2(a, b2);
    hb[i] = (unsigned short)(uh & 0xFFFFu);
    hb[i + 1] = (unsigned short)(uh >> 16);
    lb[i] = (unsigned short)(ul & 0xFFFFu);
    lb[i + 1] = (unsigned short)(ul >> 16);
  }
  const size_t go = (size_t)(n0 + r) * EMB + k0 + cs;
  *(v8s*)&WTh[go] = *(v8s*)&hb[0];
  *(v8s*)&WTh[go + 8] = *(v8s*)&hb[8];
  if (wlo) {
    *(v8s*)&WTl[go] = *(v8s*)&lb[0];
    *(v8s*)&WTl[go + 8] = *(v8s*)&lb[8];
  }
}

// ------------- 128x128 GEMM (Ah*Bh [+ Ah*Bl]), gload_lds staging -------------
struct alignas(16) G2Smem {
  unsigned short Ah[128][32], Bh[128][32], Bl[128][32];  // 24KB
};

__device__ __forceinline__ void gemm128_bf(
    const unsigned short* __restrict__ Ah_g,
    const unsigned short* __restrict__ Bh_g,
    const unsigned short* __restrict__ Bl_g,
    int m0, int n0, G2Smem& S, v4f acc[4][4], const bool useBl) {
  const int t = threadIdx.x;
  const int l = t & 63, w = t >> 6;
  const int wm = (w >> 1) << 6, wn = (w & 1) << 6;
  const int lg = l >> 4, lc = l & 15;
  const int r0 = t >> 2;
  const int gl = (t & 3) ^ ((r0 >> 1) & 3);
  unsigned short* lba = &S.Ah[0][0] + w * 512;
  unsigned short* lbb = &S.Bh[0][0] + w * 512;
  unsigned short* lbl = &S.Bl[0][0] + w * 512;
  for (int k0 = 0; k0 < EMB; k0 += 32) {
    __syncthreads();
    {
      const size_t sa0 = (size_t)(m0 + r0) * EMB + k0 + gl * 8;
      const size_t sb0 = (size_t)(n0 + r0) * EMB + k0 + gl * 8;
      gload16(Ah_g + sa0, lba);
      gload16(Ah_g + sa0 + (size_t)64 * EMB, lba + 2048);
      gload16(Bh_g + sb0, lbb);
      gload16(Bh_g + sb0 + (size_t)64 * EMB, lbb + 2048);
      if (useBl) {
        gload16(Bl_g + sb0, lbl);
        gload16(Bl_g + sb0 + (size_t)64 * EMB, lbl + 2048);
      }
    }
    asm volatile("s_waitcnt vmcnt(0)" ::: "memory");
    __syncthreads();
    v8s ah[4], bh[4], bl[4];
#pragma unroll
    for (int r = 0; r < 4; ++r) {
      const int ra = wm + r * 16 + lc;
      ah[r] = *(const v8s*)&S.Ah[ra][(lg ^ ((ra >> 1) & 3)) * 8];
      const int rb = wn + r * 16 + lc;
      bh[r] = *(const v8s*)&S.Bh[rb][(lg ^ ((rb >> 1) & 3)) * 8];
      if (useBl) bl[r] = *(const v8s*)&S.Bl[rb][(lg ^ ((rb >> 1) & 3)) * 8];
    }
#pragma unroll
    for (int i = 0; i < 4; ++i)
#pragma unroll
      for (int j = 0; j < 4; ++j) {
        acc[i][j] = mfma16(ah[i], bh[j], acc[i][j]);
        if (useBl) acc[i][j] = mfma16(ah[i], bl[j], acc[i][j]);
      }
  }
  __syncthreads();  // LDS safe to reuse
}

// ---------------- kernel: QKV projection -------------------------------------
__global__ __launch_bounds__(256) void qkv_mfma(
    const float* __restrict__ bq, const float* __restrict__ bk,
    const float* __restrict__ bv, unsigned short* __restrict__ wsu) {
  __shared__ G2Smem S;
  const int mat = blockIdx.y >> 3;
  const int m0 = blockIdx.x << 7, n0 = (blockIdx.y & 7) << 7;
  const unsigned short* Ah_g = wsu + 32u * MU;
  const unsigned short* Bh_g = wsu + (size_t)(40u + 2u * mat) * MU;
  const unsigned short* Bl_g = Bh_g + MU;
  const float* bias = (mat == 0) ? bq : (mat == 1) ? bk : bv;
  unsigned short* oh = wsu + (size_t)mat * 8u * MU;  // q:0 k:8 v(t):16
  unsigned short* ol = oh + 4u * MU;

  v4f acc[4][4] = {};
  gemm128_bf(Ah_g, Bh_g, Bl_g, m0, n0, S, acc, mat == 0);

  const int t = threadIdx.x, l = t & 63, w = t >> 6;
  const int wm = (w >> 1) << 6, wn = (w & 1) << 6, lg = l >> 4, lc = l & 15;
  if (mat == 0) {  // Q: plain [bh][s][d], hi+lo
#pragma unroll
    for (int i = 0; i < 4; ++i)
#pragma unroll
      for (int j = 0; j < 4; ++j)
#pragma unroll
        for (int jr = 0; jr < 4; ++jr) {
          const int r = m0 + wm + i * 16 + lg * 4 + jr;
          const int cm = n0 + wn + j * 16 + lc;
          const float val = acc[i][j][jr] + bias[cm] * (0.125f * LOG2E);
          const unsigned short h = bfh(val);
          const size_t idx = (((size_t)((r >> 11) * NH + (cm >> 6)) * SEQ) +
                              (r & 2047)) * HD + (cm & 63);
          oh[idx] = h;
          ol[idx] = bfh(val - bff(h));
        }
  } else if (mat == 1) {  // K: swizzled granules (period-32 key), hi only
#pragma unroll
    for (int i = 0; i < 4; ++i)
#pragma unroll
      for (int j = 0; j < 4; ++j)
#pragma unroll
        for (int jr = 0; jr < 4; ++jr) {
          const int r = m0 + wm + i * 16 + lg * 4 + jr;
          const int cm = n0 + wn + j * 16 + lc;
          const float val = acc[i][j][jr] + bias[cm];
          const int s = r & 2047, d = cm & 63;
          const size_t idx = (((size_t)((r >> 11) * NH + (cm >> 6)) * SEQ) + s) * HD +
                             ((((d >> 3) ^ skey(s)) << 3) | (d & 7));
          oh[idx] = bfh(val);
        }
  } else {  // V: transpose via LDS -> [bh][d][s] swizzled (period-32 key), hi only
    unsigned short* Traw = &S.Ah[0][0];
    unsigned short (*Th)[136] = (unsigned short(*)[136])Traw;
    const int b = m0 >> 11;
    const int s0base = m0 & 2047;
#pragma unroll
    for (int j = 0; j < 4; ++j) {
      __syncthreads();
#pragma unroll
      for (int i = 0; i < 4; ++i)
#pragma unroll
        for (int jr = 0; jr < 4; ++jr) {
          const int cm = n0 + wn + j * 16 + lc;
          const float val = acc[i][j][jr] + bias[cm];
          const int trow = (wn >> 2) + lc;
          const int tcol = wm + i * 16 + lg * 4 + jr;
          Th[trow][tcol] = bfh(val);
        }
      __syncthreads();
      const int tr = t >> 3, sgc = (t & 7) * 16;
      const int c = n0 + (tr >> 4) * 64 + j * 16 + (tr & 15);
      const int h2 = c >> 6, d = c & 63;
      const int sabs = s0base + sgc;
      const int g0 = (sabs >> 3) & 7;  // even
      const size_t ob = ((size_t)(b * NH + h2) * HD + d) * SEQ + (sabs & ~63);
      const int o0 = (g0 ^ skey(d)) << 3, o1 = ((g0 + 1) ^ skey(d)) << 3;
      *(v8s*)&oh[ob + o0] = *(const v8s*)&Th[tr][sgc];
      *(v8s*)&oh[ob + o1] = *(const v8s*)&Th[tr][sgc + 8];
    }
  }
}

// ---------------- kernel: flash attention (KV-split 2x) ----------------------
__device__ __forceinline__ v8s pfrag(unsigned a0, unsigned a1, unsigned a2,
                                     unsigned a3, int h5) {
  const unsigned sa = (unsigned)__shfl_xor((int)(h5 ? a0 : a2), 32, 64);
  const unsigned sb = (unsigned)__shfl_xor((int)(h5 ? a1 : a3), 32, 64);
  v4u r;
  r[0] = h5 ? sa : a0;
  r[1] = h5 ? sb : a1;
  r[2] = h5 ? a2 : sa;
  r[3] = h5 ? a3 : sb;
  return __builtin_bit_cast(v8s, r);
}

__global__ __launch_bounds__(256, 4) void attn_mfma(
    const float* __restrict__ rel_bias, unsigned short* __restrict__ wsu) {
  __shared__ struct alignas(16) {
    unsigned short Kh[2][64][64];
    unsigned short VTh[2][64][64];
    float bias8[32];
  } S;
  const int t = threadIdx.x;
  const int nid = (blockIdx.x & 7) * 128 + (blockIdx.x >> 3);  // XCD swizzle
  const int half = nid >> 9;
  const int bh = (nid >> 4) & 31;
  const int qt = nid & 15;
  const int hh = bh & 15;
  const int w = t >> 6, l = t & 63;
  const int lq = l & 31, h5 = l >> 5;
  const int qbase = qt * 128 + w * 32;
  const int kvbase = half << 10;
  const int kkey = skey(lq);

  const unsigned short* qh = wsu;
  const unsigned short* ql = wsu + 4u * MU;
  const unsigned short* kh = wsu + 8u * MU;
  const unsigned short* vth = wsu + 16u * MU;
  unsigned short* odT = wsu + (half ? 28u : 24u) * MU;  // [bh][d][s]
  float* stats = (float*)(wsu + 36u * MU);

  if (t < 32) S.bias8[t] = rel_bias[t * NH + hh] * 8.0f * LOG2E;

  v8s qfh[4], qfl[4];
  const size_t qg = ((size_t)bh * SEQ + qbase + lq) * HD;
#pragma unroll
  for (int dc = 0; dc < 4; ++dc) {
    qfh[dc] = *(const v8s*)(qh + qg + dc * 16 + h5 * 8);
    qfl[dc] = *(const v8s*)(ql + qg + dc * 16 + h5 * 8);
  }

  float l_run = 0.0f;
  v16f acc[2] = {};

  const int srow = t >> 3, sg = t & 7;
  const size_t kbase_g = ((size_t)bh * SEQ + kvbase) * HD;
  const size_t vbase_g = (size_t)bh * HD * SEQ + kvbase;

  auto stage = [&](int kt, int bufsel) {
    const int kv0 = kt * 64;
    unsigned short* lk = &S.Kh[bufsel][0][0] + w * 512;
    unsigned short* lvh = &S.VTh[bufsel][0][0] + w * 512;
    gload16(kh + kbase_g + (size_t)(kv0 + srow) * HD + sg * 8, lk);
    gload16(kh + kbase_g + (size_t)(kv0 + srow + 32) * HD + sg * 8, lk + 2048);
    gload16(vth + vbase_g + (size_t)srow * SEQ + kv0 + sg * 8, lvh);
    gload16(vth + vbase_g + (size_t)(srow + 32) * SEQ + kv0 + sg * 8, lvh + 2048);
  };

  stage(0, 0);
  for (int kt = 0; kt < 16; ++kt) {
    const int buf = kt & 1;
    const int kv0 = kvbase + kt * 64;
    asm volatile("s_waitcnt vmcnt(0)" ::: "memory");
    __syncthreads();
    if (kt < 15) stage(kt + 1, buf ^ 1);

    // ---- QK^T swapped, 2-pass (Kh*Qh + Kh*Ql) ----
    v16f sc[2] = {};
    __builtin_amdgcn_s_setprio(1);
#pragma unroll
    for (int kb = 0; kb < 2; ++kb)
#pragma unroll
      for (int dc = 0; dc < 4; ++dc) {
        const int cswz = (((dc << 1) + h5) ^ kkey) << 3;
        const v8s kfh = *(const v8s*)&S.Kh[buf][kb * 32 + lq][cswz];
        sc[kb] = mfma32(kfh, qfh[dc], sc[kb]);
        sc[kb] = mfma32(kfh, qfl[dc], sc[kb]);
      }
    __builtin_amdgcn_s_setprio(0);

    // ---- fixed-base softmax: p = exp2(sc + bias - CBASE), no max tracking ----
    float rs = 0.0f;
    unsigned pk[16];
#pragma unroll
    for (int kb = 0; kb < 2; ++kb) {
      const int dq = qbase - (kv0 + kb * 32);
      float base;
      if (dq + 31 <= 0) {
        base = CBASE - S.bias8[0];       // uniform bias folded into exp base
      } else if (dq >= 90) {
        base = CBASE - S.bias8[31];
      } else {
        base = CBASE;
#pragma unroll
        for (int r = 0; r < 16; ++r) {   // banded tiles: per-element bucket
          const int krow = (r & 3) + 8 * (r >> 2) + 4 * h5;
          int rp = (qbase + lq) - (kv0 + kb * 32 + krow);
          rp = rp > 0 ? rp : 0;
          const int bu =
              rp < 16 ? rp
                      : imin(16 + (int)(8.0f * __log2f((float)rp * 0.0625f)), 31);
          sc[kb][r] += S.bias8[bu];
        }
      }
      float p[16];
#pragma unroll
      for (int r = 0; r < 16; ++r) p[r] = exp2a(sc[kb][r] - base);
      const float s0 = (p[0] + p[1]) + (p[2] + p[3]);
      const float s1 = (p[4] + p[5]) + (p[6] + p[7]);
      const float s2 = (p[8] + p[9]) + (p[10] + p[11]);
      const float s3 = (p[12] + p[13]) + (p[14] + p[15]);
      rs += (s0 + s1) + (s2 + s3);
#pragma unroll
      for (int i = 0; i < 8; ++i) pk[kb * 8 + i] = pk2(p[2 * i], p[2 * i + 1]);
    }
    rs += __shfl_xor(rs, 32, 64);
    l_run += rs;

    // ---- PV 1-pass (Ph*Vh), O^T accumulate ----
    __builtin_amdgcn_s_setprio(1);
#pragma unroll
    for (int ks = 0; ks < 4; ++ks) {
      const v8s pb = pfrag(pk[4 * ks], pk[4 * ks + 1], pk[4 * ks + 2],
                           pk[4 * ks + 3], h5);
      const int vswz = (((ks << 1) + h5) ^ kkey) << 3;
#pragma unroll
      for (int db = 0; db < 2; ++db) {
        const v8s vfh = *(const v8s*)&S.VTh[buf][db * 32 + lq][vswz];
        acc[db] = mfma32(vfh, pb, acc[db]);
      }
    }
    __builtin_amdgcn_s_setprio(0);
  }

  // epilogue: coalesced O^T partial write + l stat
  const float inv = 1.0f / l_run;
  const size_t ob = (size_t)bh * HD * SEQ;
#pragma unroll
  for (int db = 0; db < 2; ++db)
#pragma unroll
    for (int r = 0; r < 16; ++r) {
      const int d = db * 32 + (r & 3) + 8 * (r >> 2) + 4 * h5;
      odT[ob + (size_t)d * SEQ + qbase + lq] = bfh(acc[db][r] * inv);
    }
  if (h5 == 0)
    stats[(size_t)((half << 5) + bh) * SEQ + qbase + lq] = l_run;
}

// ---------------- kernel: merge halves + transpose O^T -> ctx ----------------
__global__ __launch_bounds__(256) void merge_kernel(unsigned short* __restrict__ wsu) {
  __shared__ unsigned short T[64][72];  // [s-local][d]
  __shared__ float2 AB[64];             // per-s blend factors (a0, a1)
  const int t = threadIdx.x;
  const int s0 = blockIdx.x * 64;  // 32
  const int bh = blockIdx.y;       // 32
  const int b = bh >> 4, hh = bh & 15;
  const unsigned short* o0 = wsu + 24u * MU;
  const unsigned short* o1 = wsu + 28u * MU;
  unsigned short* ctx = wsu + 32u * MU;
  const float* st = (const float*)(wsu + 36u * MU);
  if (t < 64) {
    const float l0 = st[(size_t)bh * SEQ + s0 + t];
    const float l1 = st[(size_t)(32 + bh) * SEQ + s0 + t];
    const float inv = 1.0f / (l0 + l1);
    AB[t] = make_float2(l0 * inv, l1 * inv);
  }
  __syncthreads();
  const int r = t >> 2, cs = (t & 3) * 16;  // r = d row, cs = s offset
  const size_t g = ((size_t)bh * HD + r) * SEQ + s0 + cs;
  const v8s x0a = *(const v8s*)(o0 + g), x0b = *(const v8s*)(o0 + g + 8);
  const v8s x1a = *(const v8s*)(o1 + g), x1b = *(const v8s*)(o1 + g + 8);
#pragma unroll
  for (int i = 0; i < 8; ++i) {
    const float2 ab0 = AB[cs + i];
    T[cs + i][r] = bfh(ab0.x * bff((unsigned short)x0a[i]) +
                       ab0.y * bff((unsigned short)x1a[i]));
    const float2 ab1 = AB[cs + 8 + i];
    T[cs + 8 + i][r] = bfh(ab1.x * bff((unsigned short)x0b[i]) +
                           ab1.y * bff((unsigned short)x1b[i]));
  }
  __syncthreads();
  // write ctx [b][s][E]: row = s0 + r, cols hh*64 + cs..cs+16
  const size_t co = ((size_t)b * SEQ + s0 + r) * EMB + hh * HD + cs;
  *(v8s*)&ctx[co] = *(const v8s*)&T[r][cs];
  *(v8s*)&ctx[co + 8] = *(const v8s*)&T[r][cs + 8];
}

// ---------------- kernel: output projection (1-pass) -------------------------
__global__ __launch_bounds__(256) void out_mfma(
    const float* __restrict__ bo, float* __restrict__ out,
    unsigned short* __restrict__ wsu) {
  __shared__ G2Smem S;
  const int m0 = blockIdx.x << 7, n0 = blockIdx.y << 7;
  const unsigned short* Ah_g = wsu + 32u * MU;  // merged ctx (bf16 hi)
  const unsigned short* Bh_g = wsu + 46u * MU;
  const unsigned short* Bl_g = wsu + 47u * MU;
  v4f acc[4][4] = {};
  gemm128_bf(Ah_g, Bh_g, Bl_g, m0, n0, S, acc, false);
  const int t = threadIdx.x, l = t & 63, w = t >> 6;
  const int wm = (w >> 1) << 6, wn = (w & 1) << 6, lg = l >> 4, lc = l & 15;
#pragma unroll
  for (int i = 0; i < 4; ++i)
#pragma unroll
    for (int j = 0; j < 4; ++j)
#pragma unroll
      for (int jr = 0; jr < 4; ++jr) {
        const int r = m0 + wm + i * 16 + lg * 4 + jr;
        const int c = n0 + wn + j * 16 + lc;
        out[(size_t)r * EMB + c] = acc[i][j][jr] + bo[c];
      }
}

extern "C" void kernel_launch(void* const* d_in, const int* in_sizes, int n_in,
                              void* d_out, int out_size, void* d_ws, size_t ws_size,
                              hipStream_t stream) {
  const float* hs = (const float*)d_in[0];
  const float* Wq = (const float*)d_in[1];
  const float* bq = (const float*)d_in[2];
  const float* Wk = (const float*)d_in[3];
  const float* bk = (const float*)d_in[4];
  const float* Wv = (const float*)d_in[5];
  const float* bv = (const float*)d_in[6];
  const float* Wo = (const float*)d_in[7];
  const float* bo = (const float*)d_in[8];
  const float* rb = (const float*)d_in[9];
  unsigned short* wsu = (unsigned short*)d_ws;

  hipLaunchKernelGGL(prep_kernel, dim3(16, 16, 5), dim3(256), 0, stream,
                     hs, Wq, Wk, Wv, Wo, wsu);
  hipLaunchKernelGGL(qkv_mfma, dim3(32, 24), dim3(256), 0, stream, bq, bk, bv, wsu);
  hipLaunchKernelGGL(attn_mfma, dim3(1024), dim3(256), 0, stream, rb, wsu);
  hipLaunchKernelGGL(merge_kernel, dim3(32, 32), dim3(256), 0, stream, wsu);
  hipLaunchKernelGGL(out_mfma, dim3(32, 8), dim3(256), 0, stream, bo, (float*)d_out, wsu);
}